// Round 13
// baseline (246.008 us; speedup 1.0000x reference)
//
#include <hip/hip_runtime.h>
#include <stdint.h>

// ============================================================================
// MessagePassing collapse:
//   e2 = (3+a_vc)*base,  base = LN((scores*softmax_e(scores)) @ Wp_vc^T)
//   n2 = (1+a)^3 * features + (1-a)((1+a)^2+(1+a)+1) * nb,  a = ec_alpha
//   nb = LN((inc @ base) @ Wp_ec^T)  (LN positive-scale-invariant)
//   EC's MHA is dead code.
// R22: R21 resubmitted verbatim (R21 hit an infra failure, never ran).
// = R14 (best verified: 241.8us) + nontemporal out_inc stores via f32x4
// (48MB write-once stream; keep L2 for incb/incT re-reads).
// ============================================================================

#define DEV static __device__ __forceinline__

typedef __attribute__((ext_vector_type(8))) short bf16x8;
typedef __attribute__((ext_vector_type(4))) float f32x4;

DEV uint16_t f2bf(float x){
  union{float f; uint32_t u;} v; v.f=x;
  uint32_t r = v.u + 0x7fffu + ((v.u>>16)&1u);
  return (uint16_t)(r>>16);
}
DEV float bf2f(uint16_t b){
  union{uint32_t u; float f;} v; v.u=((uint32_t)b)<<16; return v.f;
}

DEV uint32_t cvtpk_bf16(float lo, float hi){
  uint32_t d;
  asm("v_cvt_pk_bf16_f32 %0, %1, %2" : "=v"(d) : "v"(lo), "v"(hi));
  return d;
}

#if __has_builtin(__builtin_amdgcn_exp2f)
DEV float exp2fast(float x){ return __builtin_amdgcn_exp2f(x); }
#else
DEV float exp2fast(float x){ return __expf(x * 0.6931471805599453f); }
#endif

#if __has_builtin(__builtin_amdgcn_global_load_lds)
#define HAVE_GLL 1
#else
#define HAVE_GLL 0
#endif

DEV void load_lds16(const uint16_t* g, void* l){
#if HAVE_GLL
  __builtin_amdgcn_global_load_lds((const __attribute__((address_space(1))) uint32_t*)g,
                                   (__attribute__((address_space(3))) uint32_t*)l, 16, 0, 0);
#else
  *(bf16x8*)l = *(const bf16x8*)g;
#endif
}

DEV void store_nt_f4(float4 v, float* p){
#if __has_builtin(__builtin_nontemporal_store)
  f32x4 x = {v.x, v.y, v.z, v.w};
  __builtin_nontemporal_store(x, (f32x4*)p);
#else
  *(float4*)p = v;
#endif
}

// ---------------------------------------------------------------------------
// Front launch, 3 block ranges:
//  [0,384):      qkv GEMM C[8192,768] = feats(f32)@Win(f32)^T + bin;
//                tile 128x128, BK=32, reg-staged f32->bf16 (cvt_pk).
//  [384,3456):   inc prep, vectorized: 64rows x 64cols per block
//                (float4 copy out [nontemporal] + u64 bf16 + transposed
//                uint4 bf16 via LDS f32[64][65]).
//  [3456,3648):  Wout/Wpv/Wpe f32->bf16 casts (49152 f4 units).
// ---------------------------------------------------------------------------
__global__ __launch_bounds__(256, 3)
void qkv_prep(const float* __restrict__ inc, float* __restrict__ out_inc,
              uint16_t* __restrict__ incb, uint16_t* __restrict__ incT,
              const float* __restrict__ feats, const float* __restrict__ win,
              const float* __restrict__ bias, uint16_t* __restrict__ qkvb,
              const float* __restrict__ wout, const float* __restrict__ wpv,
              const float* __restrict__ wpe,
              uint16_t* __restrict__ ob_w, uint16_t* __restrict__ ov_w,
              uint16_t* __restrict__ oe_w){
  __shared__ union {
    struct { short As[128*32]; short Bs[128*32]; } g;   // 16 KB
    float T[64*65];                                     // 16.6 KB
  } sm;
  const int tid = threadIdx.x;
  const int bx = blockIdx.x;

  if (bx < 384){
    // ---- qkv GEMM, BK=32 ----
    const int lane = tid & 63;
    const int w = tid >> 6;
    const int wm = w & 1, wn = w >> 1;
    const int r = lane & 15, q = lane >> 4;
    const int mtile = bx & 63, ntile = bx >> 6;   // 64 x 6
    const float* Fb = feats + (size_t)(mtile*128)*256;
    const float* Wb = win + (size_t)(ntile*128)*256;
    f32x4 acc[4][4];
#pragma unroll
    for (int i=0;i<4;++i)
#pragma unroll
      for (int j=0;j<4;++j) acc[i][j] = (f32x4){0.f,0.f,0.f,0.f};

    const int srow = tid >> 2;   // 0..63
    const int sblk = tid & 3;    // 0..3 (units of 8 bf16 within BK=32)

    for (int kb = 0; kb < 256; kb += 32){
#pragma unroll
      for (int i=0;i<2;++i){
        int row = srow + 64*i;
        const float* src = Fb + (size_t)row*256 + kb + sblk*8;
        float4 a0 = *(const float4*)src;
        float4 a1 = *(const float4*)(src+4);
        union{uint32_t u[4]; bf16x8 v8;} pk;
        pk.u[0]=cvtpk_bf16(a0.x,a0.y); pk.u[1]=cvtpk_bf16(a0.z,a0.w);
        pk.u[2]=cvtpk_bf16(a1.x,a1.y); pk.u[3]=cvtpk_bf16(a1.z,a1.w);
        *(bf16x8*)&sm.g.As[row*32 + (sblk ^ (row&3))*8] = pk.v8;
      }
#pragma unroll
      for (int i=0;i<2;++i){
        int row = srow + 64*i;
        const float* src = Wb + (size_t)row*256 + kb + sblk*8;
        float4 a0 = *(const float4*)src;
        float4 a1 = *(const float4*)(src+4);
        union{uint32_t u[4]; bf16x8 v8;} pk;
        pk.u[0]=cvtpk_bf16(a0.x,a0.y); pk.u[1]=cvtpk_bf16(a0.z,a0.w);
        pk.u[2]=cvtpk_bf16(a1.x,a1.y); pk.u[3]=cvtpk_bf16(a1.z,a1.w);
        *(bf16x8*)&sm.g.Bs[row*32 + (sblk ^ (row&3))*8] = pk.v8;
      }
      __syncthreads();
      bf16x8 af[4], bfr[4];
#pragma unroll
      for (int mt=0;mt<4;++mt){
        int m = wm*64 + mt*16 + r;
        af[mt] = *(const bf16x8*)&sm.g.As[m*32 + (q ^ (m&3))*8];
      }
#pragma unroll
      for (int nt=0;nt<4;++nt){
        int n = wn*64 + nt*16 + r;
        bfr[nt] = *(const bf16x8*)&sm.g.Bs[n*32 + (q ^ (n&3))*8];
      }
#pragma unroll
      for (int mt=0;mt<4;++mt)
#pragma unroll
        for (int nt=0;nt<4;++nt)
          acc[mt][nt] = __builtin_amdgcn_mfma_f32_16x16x32_bf16(af[mt], bfr[nt], acc[mt][nt], 0,0,0);
      __syncthreads();
    }

    const int gm0 = mtile*128 + wm*64;
    const int gn0 = ntile*128 + wn*64;
#pragma unroll
    for (int mt=0;mt<4;++mt){
#pragma unroll
      for (int nt=0;nt<4;++nt){
        int gn = gn0 + nt*16 + r;
        float bv = bias[gn];
#pragma unroll
        for (int reg=0;reg<4;++reg){
          int gm = gm0 + mt*16 + q*4 + reg;   // C/D: col=lane&15, row=quad*4+reg
          qkvb[(size_t)gm*768 + gn] = f2bf(acc[mt][nt][reg] + bv);
        }
      }
    }
  } else if (bx < 3456){
    // ---- inc prep, vectorized 64x64 tile ----
    int p = bx - 384;
    int x = p % 24;             // 64-col tile (1536/64)
    int t = p / 24;
    int y = t & 15;             // 64-row tile (1024/64)
    int b = t >> 4;             // batch
    int c0 = x*64, r0 = y*64;
    int tx = tid & 15, ty = tid >> 4;   // 16 x 16
    size_t base = (size_t)b*1024*1536;
#pragma unroll
    for (int jj=0;jj<4;++jj){
      int rl = ty + jj*16;
      size_t idx = base + (size_t)(r0+rl)*1536 + c0 + tx*4;
      float4 v = *(const float4*)&inc[idx];
      store_nt_f4(v, &out_inc[idx]);   // write-once, never re-read: keep L2
      union{uint16_t u[4]; uint64_t q64;} pk;
      pk.u[0]=f2bf(v.x); pk.u[1]=f2bf(v.y); pk.u[2]=f2bf(v.z); pk.u[3]=f2bf(v.w);
      *(uint64_t*)&incb[idx] = pk.q64;
      float* Tp = &sm.T[rl*65 + tx*4];
      Tp[0]=v.x; Tp[1]=v.y; Tp[2]=v.z; Tp[3]=v.w;
    }
    __syncthreads();
    // transposed write: c = tid>>2 (0..63 e-rows), ms = (tid&3)*16 m-offset;
    // lanes 0-3 cover one row's 128B contiguously.
    int c = tid >> 2, ms = (tid & 3) * 16;
    size_t baseT = (size_t)b*1536*1024;
    uint16_t* dst = incT + baseT + (size_t)(c0+c)*1024 + r0 + ms;
    union{uint16_t u[8]; uint4 v4;} o0, o1;
#pragma unroll
    for (int j=0;j<8;++j) o0.u[j] = f2bf(sm.T[(ms+j)*65 + c]);
#pragma unroll
    for (int j=0;j<8;++j) o1.u[j] = f2bf(sm.T[(ms+8+j)*65 + c]);
    *(uint4*)dst = o0.v4;
    *(uint4*)(dst+8) = o1.v4;
  } else {
    // ---- weight casts: Wout/Wpv/Wpe, 16384 f4-units each ----
    int i = (bx - 3456)*256 + tid;
    const float* src; uint16_t* dst; int j;
    if (i < 16384){ src=wout; dst=ob_w; j=i; }
    else if (i < 32768){ src=wpv; dst=ov_w; j=i-16384; }
    else { src=wpe; dst=oe_w; j=i-32768; }
    float4 v = ((const float4*)src)[j];
    union { uint16_t u[4]; uint64_t q; } p;
    p.u[0]=f2bf(v.x); p.u[1]=f2bf(v.y); p.u[2]=f2bf(v.z); p.u[3]=f2bf(v.w);
    ((uint64_t*)dst)[j] = p.q;
  }
}

// ---------------------------------------------------------------------------
// NT bf16 GEMM (LDS-staged): C[M,N] = A[M,K]*B[N,K]^T (+bias).
// EPI 1 = transposed bf16 store (per-batch [N][1024]). Used for outproj.
// ---------------------------------------------------------------------------
template<int WM, int BK, int EPI>
__global__ __launch_bounds__(256, 3)
void gemm_nt(const uint16_t* __restrict__ A, const uint16_t* __restrict__ B,
             uint16_t* __restrict__ Cb, const float* __restrict__ bias,
             int M, int N, int K){
  constexpr int AROWS = WM*32;
  constexpr int UPR = BK/8;
  constexpr int RPP = 256/UPR;
  __shared__ short As[AROWS*BK];
  __shared__ short Bs[128*BK];
  const int tid = threadIdx.x;
  const int lane = tid & 63;
  const int w = tid >> 6;
  const int wm = w & 1, wn = w >> 1;
  const int r = lane & 15, q = lane >> 4;
  const uint16_t* Ab = A + (size_t)(blockIdx.x*AROWS)*K;
  const uint16_t* Bb = B + (size_t)(blockIdx.y*128)*K;
  f32x4 acc[WM][4];
#pragma unroll
  for (int i=0;i<WM;++i)
#pragma unroll
    for (int j=0;j<4;++j) acc[i][j] = (f32x4){0.f,0.f,0.f,0.f};

  const int srow = tid / UPR;
  const int sblk = tid % UPR;

  for (int kb = 0; kb < K; kb += BK){
#pragma unroll
    for (int i=0;i<AROWS/RPP;++i){
      int row = srow + RPP*i;
      int lblk = sblk ^ (row & (UPR-1));
      load_lds16(Ab + (size_t)row*K + kb + lblk*8, (char*)As + i*4096 + tid*16);
    }
#pragma unroll
    for (int i=0;i<128/RPP;++i){
      int row = srow + RPP*i;
      int lblk = sblk ^ (row & (UPR-1));
      load_lds16(Bb + (size_t)row*K + kb + lblk*8, (char*)Bs + i*4096 + tid*16);
    }
    __syncthreads();
#pragma unroll
    for (int kc=0;kc<BK/32;++kc){
      bf16x8 af[WM], bfr[4];
#pragma unroll
      for (int mt=0;mt<WM;++mt){
        int m = wm*(WM*16) + mt*16 + r;
        af[mt] = *(const bf16x8*)&As[m*BK + ((kc*4 + q) ^ (m&(UPR-1)))*8];
      }
#pragma unroll
      for (int nt=0;nt<4;++nt){
        int n = wn*64 + nt*16 + r;
        bfr[nt] = *(const bf16x8*)&Bs[n*BK + ((kc*4 + q) ^ (n&(UPR-1)))*8];
      }
#pragma unroll
      for (int mt=0;mt<WM;++mt)
#pragma unroll
        for (int nt=0;nt<4;++nt)
          acc[mt][nt] = __builtin_amdgcn_mfma_f32_16x16x32_bf16(af[mt], bfr[nt], acc[mt][nt], 0,0,0);
    }
    __syncthreads();
  }

  const int gm0 = blockIdx.x*AROWS + wm*(WM*16);
  const int gn0 = blockIdx.y*128 + wn*64;

  if constexpr (EPI == 1){
#pragma unroll
    for (int mt=0;mt<WM;++mt){
      int gmb = gm0 + mt*16 + q*4;
      size_t bb_ = (size_t)(gmb>>10)*(256*1024);
      int mm = gmb & 1023;
#pragma unroll
      for (int nt=0;nt<4;++nt){
        int gn = gn0 + nt*16 + r;
        float bv = bias ? bias[gn] : 0.f;
        union{uint16_t u[4]; uint64_t q64;} pk;
#pragma unroll
        for (int reg=0;reg<4;++reg) pk.u[reg] = f2bf(acc[mt][nt][reg] + bv);
        *(uint64_t*)(Cb + bb_ + (size_t)gn*1024 + mm) = pk.q64;
      }
    }
  } else {
#pragma unroll
    for (int mt=0;mt<WM;++mt){
#pragma unroll
      for (int nt=0;nt<4;++nt){
        int gn = gn0 + nt*16 + r;
        float bv = bias ? bias[gn] : 0.f;
#pragma unroll
        for (int reg=0;reg<4;++reg){
          int gm = gm0 + mt*16 + q*4 + reg;
          Cb[(size_t)gm*N + gn] = f2bf(acc[mt][nt][reg] + bv);
        }
      }
    }
  }
}

// ---------------------------------------------------------------------------
// scores GEMM: C[e,d] = incT[e,:].attnT[d,:] (K=1024). Tile 32e x 128d,
// 4 waves x 32 cols. Grid 768 = 8 batches * 48 etiles * 2 dhalves,
// XCD-swizzled. Writes VE=v*exp(v) bf16 + column exp-sum partials
// (48 partials per column, layout part[batch][48][256]).
// ---------------------------------------------------------------------------
__global__ __launch_bounds__(256, 4)
void gemm_score(const uint16_t* __restrict__ A,   // INCT flat [8*1536][1024]
                const uint16_t* __restrict__ B,   // ATTNT [8][256][1024]
                float* __restrict__ part,         // [8][48][256]
                uint16_t* __restrict__ VE){       // [8*1536][256]
  __shared__ short As[32*64];     // 4 KB
  __shared__ short Bs[128*64];    // 16 KB
  const int tid = threadIdx.x;
  const int lane = tid & 63;
  const int w = tid >> 6;
  const int r = lane & 15, q = lane >> 4;
  const int bx = (blockIdx.x & 7)*96 + (blockIdx.x >> 3);   // bijective, 768=8*96
  const int batch = bx / 96;
  const int t = bx % 96;
  const int etile = t >> 1, dh = t & 1;
  const uint16_t* Ab = A + (size_t)(batch*1536 + etile*32)*1024;
  const uint16_t* Bb = B + (size_t)(batch*256 + dh*128)*1024;

  f32x4 acc[2][2];
#pragma unroll
  for (int i=0;i<2;++i)
#pragma unroll
    for (int j=0;j<2;++j) acc[i][j] = (f32x4){0.f,0.f,0.f,0.f};

  const int srow = tid >> 3;   // 0..31
  const int sblk = tid & 7;

  for (int kb = 0; kb < 1024; kb += 64){
    { int lblk = sblk ^ (srow & 7);
      load_lds16(Ab + (size_t)srow*1024 + kb + lblk*8, (char*)As + tid*16); }
#pragma unroll
    for (int i=0;i<4;++i){
      int row = srow + 32*i;
      int lblk = sblk ^ (row & 7);
      load_lds16(Bb + (size_t)row*1024 + kb + lblk*8, (char*)Bs + i*4096 + tid*16);
    }
    __syncthreads();
#pragma unroll
    for (int kc=0;kc<2;++kc){
      bf16x8 af[2], bfr[2];
#pragma unroll
      for (int mt=0;mt<2;++mt){
        int m = mt*16 + r;
        af[mt] = *(const bf16x8*)&As[m*64 + ((kc*4 + q) ^ (m&7))*8];
      }
#pragma unroll
      for (int nt=0;nt<2;++nt){
        int n = w*32 + nt*16 + r;
        bfr[nt] = *(const bf16x8*)&Bs[n*64 + ((kc*4 + q) ^ (n&7))*8];
      }
#pragma unroll
      for (int mt=0;mt<2;++mt)
#pragma unroll
        for (int nt=0;nt<2;++nt)
          acc[mt][nt] = __builtin_amdgcn_mfma_f32_16x16x32_bf16(af[mt], bfr[nt], acc[mt][nt], 0,0,0);
    }
    __syncthreads();
  }

  const size_t er0 = (size_t)batch*1536 + etile*32;
#pragma unroll
  for (int nt=0;nt<2;++nt){
    int gn = dh*128 + w*32 + nt*16 + r;
    float s = 0.f;
#pragma unroll
    for (int mt=0;mt<2;++mt){
#pragma unroll
      for (int reg=0;reg<4;++reg){
        float v = acc[mt][nt][reg];
        float ev = __expf(v);
        s += ev;
        int row = mt*16 + q*4 + reg;
        VE[(er0 + row)*256 + gn] = f2bf(v*ev);
      }
    }
    s += __shfl_xor(s, 16);
    s += __shfl_xor(s, 32);
    if (q == 0) part[(size_t)(batch*48 + etile)*256 + gn] = s;
  }
}

// ---------------------------------------------------------------------------
// Edge path: A = VE * (1/L) staged (cvt_pk), L folded from 48 partials.
// Tile 16m x 256n (LN over full 256 in-block), grid 768 = 8*96, XCD-swizzled.
// Writes out_edge f32 + BASET bf16 [b][d][e].
// ---------------------------------------------------------------------------
__global__ __launch_bounds__(256, 4)
void gemm_ln_edge(const uint16_t* __restrict__ SB, const uint16_t* __restrict__ B,
                  const float* __restrict__ part, const float* __restrict__ g,
                  const float* __restrict__ bb, const float* __restrict__ alpha,
                  float* __restrict__ out, uint16_t* __restrict__ baset){
  __shared__ short As[16*64];     // 2 KB
  __shared__ short Bs[256*64];    // 32 KB
  __shared__ float lnS[4][16], lnQ[4][16];
  __shared__ float PLinv[256];
  const int tid = threadIdx.x;
  const int lane = tid & 63;
  const int w = tid >> 6;          // wave = d-strip 0..3
  const int r = lane & 15, q = lane >> 4;
  const int bx = (blockIdx.x & 7)*96 + (blockIdx.x >> 3);   // 768=8*96
  const int batch = bx / 96;

  {
    float s = 0.f;
#pragma unroll
    for (int i=0;i<48;++i) s += part[((size_t)batch*48 + i)*256 + tid];
    PLinv[tid] = 1.0f / s;
  }
  __syncthreads();

  f32x4 acc[4];
#pragma unroll
  for (int j=0;j<4;++j) acc[j] = (f32x4){0.f,0.f,0.f,0.f};

  const int srow = tid >> 3;   // 0..31 (A uses 0..15 via tid<128)
  const int sblk = tid & 7;

  for (int kb = 0; kb < 256; kb += 64){
    if (tid < 128){
      bf16x8 v = *(const bf16x8*)(SB + (size_t)(bx*16 + srow)*256 + kb + sblk*8);
      const float* Lp = &PLinv[kb + sblk*8];
      float xv[8];
#pragma unroll
      for (int j=0;j<8;++j) xv[j] = bf2f((uint16_t)v[j]) * Lp[j];
      union{uint32_t u[4]; bf16x8 v8;} pk;
      pk.u[0] = cvtpk_bf16(xv[0], xv[1]);
      pk.u[1] = cvtpk_bf16(xv[2], xv[3]);
      pk.u[2] = cvtpk_bf16(xv[4], xv[5]);
      pk.u[3] = cvtpk_bf16(xv[6], xv[7]);
      *(bf16x8*)&As[srow*64 + (sblk ^ (srow&7))*8] = pk.v8;
    }
#pragma unroll
    for (int i=0;i<8;++i){
      int row = srow + 32*i;
      int lblk = sblk ^ (row & 7);
      load_lds16(B + (size_t)row*256 + kb + lblk*8, (char*)Bs + i*4096 + tid*16);
    }
    __syncthreads();
#pragma unroll
    for (int kc=0;kc<2;++kc){
      bf16x8 af, bfr[4];
      { int m = r;
        af = *(const bf16x8*)&As[m*64 + ((kc*4 + q) ^ (m&7))*8]; }
#pragma unroll
      for (int nt=0;nt<4;++nt){
        int n = w*64 + nt*16 + r;
        bfr[nt] = *(const bf16x8*)&Bs[n*64 + ((kc*4 + q) ^ (n&7))*8];
      }
#pragma unroll
      for (int nt=0;nt<4;++nt)
        acc[nt] = __builtin_amdgcn_mfma_f32_16x16x32_bf16(af, bfr[nt], acc[nt], 0,0,0);
    }
    __syncthreads();
  }

  // cross-wave LN reduction (rows = q*4+reg, 16 rows)
  float rs[4], rq[4];
#pragma unroll
  for (int reg=0;reg<4;++reg){
    float s=0.f, s2=0.f;
#pragma unroll
    for (int nt=0;nt<4;++nt){
      float v = acc[nt][reg];
      s += v; s2 += v*v;
    }
#pragma unroll
    for (int off=1; off<16; off<<=1){ s += __shfl_xor(s,off); s2 += __shfl_xor(s2,off); }
    rs[reg]=s; rq[reg]=s2;
  }
  if (r == 0){
#pragma unroll
    for (int reg=0;reg<4;++reg){
      int row = q*4 + reg;
      lnS[w][row] = rs[reg];
      lnQ[w][row] = rq[reg];
    }
  }
  __syncthreads();

  const float c0 = 3.0f + alpha[0];
  float mu_[4], rstd_[4];
#pragma unroll
  for (int reg=0;reg<4;++reg){
    int row = q*4 + reg;
    float S = lnS[0][row]+lnS[1][row]+lnS[2][row]+lnS[3][row];
    float Q = lnQ[0][row]+lnQ[1][row]+lnQ[2][row]+lnQ[3][row];
    float mu = S * (1.f/256.f);
    float var = fmaxf(Q*(1.f/256.f) - mu*mu, 0.f);
    mu_[reg] = mu;
    rstd_[reg] = rsqrtf(var + 1e-5f);
  }

  int e0 = (bx % 96) * 16;
#pragma unroll
  for (int nt=0;nt<4;++nt){
    int gn = w*64 + nt*16 + r;
    float gv = g[gn], bv = bb[gn];
    union{uint16_t u[4]; uint64_t q64;} pk;
#pragma unroll
    for (int reg=0;reg<4;++reg){
      int row = q*4 + reg;
      size_t gm = (size_t)bx*16 + row;
      float o = ((acc[nt][reg]-mu_[reg])*rstd_[reg]*gv + bv) * c0;
      pk.u[reg] = f2bf(o);
      out[gm*256 + gn] = o;
    }
    int ee = e0 + q*4;
    *(uint64_t*)(baset + ((size_t)batch*256 + gn)*1536 + ee) = pk.q64;
  }
}

// ---------------------------------------------------------------------------
// Fused node path: 16m x 256d tiles, grid 512 = 8 batches * 64 m-tiles,
// XCD-swizzled.
//   phase 1: W0^T[d,m] = BASET[d,:].INCB[m,:] (K=1536) -> As2 bf16 swz
//   phase 2: C2^T[d',m] = WPEB[d',:].As2[m,:] (K=256)
//   epilogue: per-m LN over d' + blend with features.
// ---------------------------------------------------------------------------
__global__ __launch_bounds__(256, 3)
void gemm_node_fused(const uint16_t* __restrict__ inc,    // INCB [8][1024][1536]
                     const uint16_t* __restrict__ baset,  // [8][256][1536]
                     const uint16_t* __restrict__ wpe,    // [256][256]
                     const float* __restrict__ g, const float* __restrict__ bb,
                     const float* __restrict__ alpha,
                     const float* __restrict__ feats, float* __restrict__ out){
  __shared__ short Ws[256*64];    // 32KB
  __shared__ short As2[16*256];   // 8KB: W0 bf16, swizzled
  __shared__ short Is[16*64];     // 2KB: inc chunk; aliased lnS/lnQ later
  const int tid = threadIdx.x;
  const int lane = tid & 63;
  const int w = tid >> 6;
  const int r = lane & 15, q = lane >> 4;
  const int bx = (blockIdx.x & 7)*64 + (blockIdx.x >> 3);  // bijective, 512=8*64
  const int batch = bx >> 6;
  const int mt0 = (bx & 63) * 16;

  const int srow = tid >> 3;   // 0..31
  const int sblk = tid & 7;

  const uint16_t* Bb = baset + (size_t)batch*256*1536;
  const uint16_t* Ib = inc + ((size_t)batch*1024 + mt0)*1536;

  f32x4 acc1[4];
#pragma unroll
  for (int i=0;i<4;++i) acc1[i] = (f32x4){0.f,0.f,0.f,0.f};

  // ---- phase 1: K=1536 ----
  for (int kb = 0; kb < 1536; kb += 64){
#pragma unroll
    for (int i=0;i<8;++i){
      int row = srow + 32*i;
      int lblk = sblk ^ (row & 7);
      load_lds16(Bb + (size_t)row*1536 + kb + lblk*8, (char*)Ws + i*4096 + tid*16);
    }
    if (tid < 128){
      int lblk = sblk ^ (srow & 7);
      load_lds16(Ib + (size_t)srow*1536 + kb + lblk*8, (char*)Is + tid*16);
    }
    __syncthreads();
#pragma unroll
    for (int kc=0;kc<2;++kc){
      bf16x8 af[4], bfr;
#pragma unroll
      for (int mt=0;mt<4;++mt){
        int d = w*64 + mt*16 + r;
        af[mt] = *(const bf16x8*)&Ws[d*64 + ((kc*4 + q) ^ (d&7))*8];
      }
      { int m = r;
        bfr = *(const bf16x8*)&Is[m*64 + ((kc*4 + q) ^ (m&7))*8]; }
#pragma unroll
      for (int mt=0;mt<4;++mt)
        acc1[mt] = __builtin_amdgcn_mfma_f32_16x16x32_bf16(af[mt], bfr, acc1[mt], 0,0,0);
    }
    __syncthreads();
  }

  // ---- W0^T -> As2[m][d] bf16, 16B-unit XOR swizzle (j ^ (m&7)) ----
  // acc1[mt][reg] = W0^T[d][m], d = w*64+mt*16+q*4+reg, m = r.
#pragma unroll
  for (int mt=0;mt<4;++mt){
    int j = w*8 + mt*2 + (q>>1);
    int m = r;
    union{uint16_t u[4]; uint64_t q64;} pk;
#pragma unroll
    for (int reg=0;reg<4;++reg) pk.u[reg] = f2bf(acc1[mt][reg]);
    *(uint64_t*)((char*)As2 + m*512 + ((j ^ (m&7))<<4) + ((q&1)<<3)) = pk.q64;
  }

  // ---- phase 2: K=256, A = WPEB, B = As2 ----
  f32x4 acc2[4];
#pragma unroll
  for (int i=0;i<4;++i) acc2[i] = (f32x4){0.f,0.f,0.f,0.f};

  for (int kb = 0; kb < 256; kb += 64){
#pragma unroll
    for (int i=0;i<8;++i){
      int row = srow + 32*i;
      int lblk = sblk ^ (row & 7);
      load_lds16(wpe + (size_t)row*256 + kb + lblk*8, (char*)Ws + i*4096 + tid*16);
    }
    __syncthreads();   // orders As2 writes + Ws restage before reads
#pragma unroll
    for (int kc=0;kc<2;++kc){
      bf16x8 af[4], bfr;
#pragma unroll
      for (int mt=0;mt<4;++mt){
        int dp = w*64 + mt*16 + r;
        af[mt] = *(const bf16x8*)&Ws[dp*64 + ((kc*4 + q) ^ (dp&7))*8];
      }
      { int m = r;
        int jr = (kb>>3) + kc*4 + q;
        bfr = *(const bf16x8*)((char*)As2 + m*512 + ((jr ^ (m&7))<<4)); }
#pragma unroll
      for (int mt=0;mt<4;++mt)
        acc2[mt] = __builtin_amdgcn_mfma_f32_16x16x32_bf16(af[mt], bfr, acc2[mt], 0,0,0);
    }
    __syncthreads();
  }

  // ---- LN over d' (per column m = r), cross-wave via LDS (alias Is) ----
  float* lnS = (float*)Is;        // [4][16]
  float* lnQ = lnS + 64;          // [4][16]
  float s_, q_;
  {
    float s=0.f, s2=0.f;
#pragma unroll
    for (int mt=0;mt<4;++mt)
#pragma unroll
      for (int reg=0;reg<4;++reg){
        float v = acc2[mt][reg];
        s += v; s2 += v*v;
      }
    s += __shfl_xor(s,16); s2 += __shfl_xor(s2,16);
    s += __shfl_xor(s,32); s2 += __shfl_xor(s2,32);
    s_ = s; q_ = s2;
  }
  if (q == 0){
    lnS[w*16 + r] = s_;
    lnQ[w*16 + r] = q_;
  }
  __syncthreads();

  const float a = alpha[0];
  const float ap1 = 1.f + a;
  const float cn = (1.f - a)*(ap1*ap1 + ap1 + 1.f);
  const float cf = ap1*ap1*ap1;

  float mu_, rstd_;
  {
    int col = r;
    float S = lnS[col] + lnS[16+col] + lnS[32+col] + lnS[48+col];
    float Q = lnQ[col] + lnQ[16+col] + lnQ[32+col] + lnQ[48+col];
    float mu = S * (1.f/256.f);
    float var = fmaxf(Q*(1.f/256.f) - mu*mu, 0.f);
    mu_ = mu;
    rstd_ = rsqrtf(var + 1e-5f);
  }

  // ---- epilogue: out[m][d'] = cf*feats + cn*LN ----
#pragma unroll
  for (int mt=0;mt<4;++mt){
    int dp0 = w*64 + mt*16 + q*4;
    float4 gv = *(const float4*)&g[dp0];
    float4 bv = *(const float4*)&bb[dp0];
    int m = r;
    size_t gm = (size_t)batch*1024 + mt0 + m;
    float4 fv = *(const float4*)&feats[gm*256 + dp0];
    float4 ov;
    ov.x = cf*fv.x + cn*((acc2[mt][0]-mu_)*rstd_*gv.x + bv.x);
    ov.y = cf*fv.y + cn*((acc2[mt][1]-mu_)*rstd_*gv.y + bv.y);
    ov.z = cf*fv.z + cn*((acc2[mt][2]-mu_)*rstd_*gv.z + bv.z);
    ov.w = cf*fv.w + cn*((acc2[mt][3]-mu_)*rstd_*gv.w + bv.w);
    *(float4*)&out[gm*256 + dp0] = ov;
  }
}

// ---------------------------------------------------------------------------
// Attention: S^T = K*Q^T (A/B frags interchangeable), packed b64 P-store,
// scalar l. 512 thr = 8 waves x 16 q-rows. grid 512 (1D, XCD-swizzled).
// Max-free softmax; exp2 direct; cvt_pk P-pack; setprio around MFMA (T5).
// ---------------------------------------------------------------------------
DEV void stage_K(short* Kl, const uint16_t* __restrict__ qkv, size_t rowbase,
                 int c, int h, int kr){
  const uint16_t* kp = qkv + ((rowbase + c*256 + kr)*768 + 256 + h*32);
  int sz = (kr&3) ^ ((kr>>2)&1);
#pragma unroll
  for (int lb=0; lb<4; ++lb){
    bf16x8 v = *(const bf16x8*)(kp + lb*8);
    *(bf16x8*)&Kl[kr*32 + ((lb ^ sz))*8] = v;
  }
}

DEV void stage_V(short* VT, const uint16_t* __restrict__ qkv, size_t rowbase,
                 int c, int h, int t){
  int kvp = (t>>1)*2;
  int dhh = (t&1)*16;
  const uint16_t* v0 = qkv + ((rowbase + c*256 + kvp)*768 + 512 + h*32 + dhh);
  const uint16_t* v1 = v0 + 768;
  bf16x8 a0 = *(const bf16x8*)(v0);
  bf16x8 a1 = *(const bf16x8*)(v0+8);
  bf16x8 b0 = *(const bf16x8*)(v1);
  bf16x8 b1 = *(const bf16x8*)(v1+8);
  int blkbase = kvp>>3, off = kvp&7;
#pragma unroll
  for (int i=0;i<8;++i){
    int dh = dhh + i;
    uint32_t pack = (uint32_t)(uint16_t)a0[i] | ((uint32_t)(uint16_t)b0[i]<<16);
    *(uint32_t*)&VT[dh*256 + ((blkbase ^ (dh&7))*8) + off] = pack;
  }
#pragma unroll
  for (int i=0;i<8;++i){
    int dh = dhh + 8 + i;
    uint32_t pack = (uint32_t)(uint16_t)a1[i] | ((uint32_t)(uint16_t)b1[i]<<16);
    *(uint32_t*)&VT[dh*256 + ((blkbase ^ (dh&7))*8) + off] = pack;
  }
}

__global__ __launch_bounds__(512)
void attn_fwd(const uint16_t* __restrict__ qkv, uint16_t* __restrict__ O){
  __shared__ short Kl[256*32];
  __shared__ short VT[32*256];
  __shared__ short Pl[8][16*36];
  const int tid = threadIdx.x, lane = tid&63, w = tid>>6;
  const int r = lane&15, q = lane>>4;
  const int logical = (blockIdx.x & 7)*64 + (blockIdx.x >> 3); // 512=8*64 bijective
  const int bh = logical >> 3, qc = logical & 7;
  const int b = bh>>3, h = bh&7;
  const int q0 = qc*128 + w*16;
  const size_t rowbase = (size_t)b*1024;

  bf16x8 aq;
  {
    // 1/sqrt(32) * log2(e): p = exp2(S_mfma)
    const float qscale = 0.25505654380651023f;
    const uint16_t* p = qkv + ((rowbase + q0 + r)*768 + h*32 + q*8);
    bf16x8 t = *(const bf16x8*)p;
#pragma unroll
    for (int j=0;j<8;++j)
      t[j] = (short)f2bf(bf2f((uint16_t)t[j]) * qscale);
    aq = t;
  }

  f32x4 o[2];
  o[0]=(f32x4){0.f,0.f,0.f,0.f}; o[1]=(f32x4){0.f,0.f,0.f,0.f};
  float l = 0.f;

  for (int c=0;c<4;++c){
    __syncthreads();
    if (tid < 256) stage_K(Kl, qkv, rowbase, c, h, tid);
    else           stage_V(VT, qkv, rowbase, c, h, tid-256);
    __syncthreads();
    for (int s32=0; s32<8; ++s32){
#pragma unroll
      for (int t2=0;t2<2;++t2){
        int rn = s32*32 + t2*16 + r;
        int sz = (rn&3) ^ ((rn>>2)&1);
        bf16x8 bk = *(const bf16x8*)&Kl[rn*32 + ((q ^ sz))*8];
        f32x4 z = (f32x4){0.f,0.f,0.f,0.f};
        __builtin_amdgcn_s_setprio(1);
        f32x4 st = __builtin_amdgcn_mfma_f32_16x16x32_bf16(bk, aq, z, 0,0,0);
        __builtin_amdgcn_s_setprio(0);
        float p0 = exp2fast(st[0]);
        float p1 = exp2fast(st[1]);
        float p2 = exp2fast(st[2]);
        float p3 = exp2fast(st[3]);
        l += (p0+p1)+(p2+p3);
        union{uint32_t u[2]; uint64_t q64;} pk;
        pk.u[0] = cvtpk_bf16(p0, p1);
        pk.u[1] = cvtpk_bf16(p2, p3);
        *(uint64_t*)&Pl[w][r*36 + t2*16 + q*4] = pk.q64;
      }
      bf16x8 bv[2];
#pragma unroll
      for (int db=0;db<2;++db){
        int dh = db*16 + r;
        bv[db] = *(const bf16x8*)&VT[dh*256 + (((s32*4 + q) ^ (dh&7)))*8];
      }
      bf16x8 ap = *(const bf16x8*)&Pl[w][r*36 + q*8];
      __builtin_amdgcn_s_setprio(1);
#pragma unroll
      for (int db=0;db<2;++db)
        o[db] = __builtin_amdgcn_mfma_f32_16x16x32_bf16(ap, bv[db], o[db], 0,0,0);
      __builtin_amdgcn_s_setprio(0);
    }
  }

  l += __shfl_xor(l, 16);
  l += __shfl_xor(l, 32);
#pragma unroll
  for (int db=0;db<2;++db)
#pragma unroll
    for (int reg=0;reg<4;++reg){
      float li = __shfl(l, q*4 + reg);
      int qr = q0 + q*4 + reg;
      O[(rowbase + qr)*256 + h*32 + db*16 + r] = f2bf(o[db][reg] / li);
    }
}

// ===========================================================================
extern "C" void kernel_launch(void* const* d_in, const int* in_sizes, int n_in,
                              void* d_out, int out_size, void* d_ws, size_t ws_size,
                              hipStream_t stream){
  const float* features = (const float*)d_in[0];
  const float* inc      = (const float*)d_in[1];
  const float* vc_Win   = (const float*)d_in[2];
  const float* vc_bin   = (const float*)d_in[3];
  const float* vc_Wout  = (const float*)d_in[4];
  const float* vc_bout  = (const float*)d_in[5];
  const float* vc_Wproj = (const float*)d_in[6];
  const float* vc_ln_g  = (const float*)d_in[7];
  const float* vc_ln_b  = (const float*)d_in[8];
  const float* vc_alpha = (const float*)d_in[9];
  const float* ec_Wproj = (const float*)d_in[14];
  const float* ec_ln_g  = (const float*)d_in[15];
  const float* ec_ln_b  = (const float*)d_in[16];
  const float* ec_alpha = (const float*)d_in[17];

  float* out = (float*)d_out;
  float* out_node = out;                 // [8,1024,256]
  float* out_edge = out + 2097152;       // [8,1536,256]
  float* out_inc  = out + 5242880;       // [8,1024,1536]

  char* ws = (char*)d_ws;
  float*    PART   = (float*)   (ws + 0);          // 393,216 (8*48*256*4)
  uint16_t* WOUTB  = (uint16_t*)(ws + 4587520);    // 131,072
  uint16_t* WPVB   = (uint16_t*)(ws + 4718592);    // 131,072
  uint16_t* WPEB   = (uint16_t*)(ws + 4849664);    // 131,072
  uint16_t* INCB   = (uint16_t*)(ws + 4988928);    // 25,165,824
  uint16_t* INCT   = (uint16_t*)(ws + 30154752);   // 25,165,824
  uint16_t* QKVB   = (uint16_t*)(ws + 55320576);   // 12,582,912
  uint16_t* SCORESB= (uint16_t*)(ws + 55320576);   // alias: QKVB dead after attn
  uint16_t* OB     = (uint16_t*)(ws + 67903488);   // 4,194,304
  uint16_t* ATTNT  = (uint16_t*)(ws + 72097792);   // 4,194,304
  uint16_t* BASET  = (uint16_t*)(ws + 82583552);   // 6,291,456 (~89 MB total)

  // front launch: qkv GEMM (f32 sources) + vectorized inc-prep + weight casts
  qkv_prep<<<3648,256,0,stream>>>(inc, out_inc, INCB, INCT,
                                  features, vc_Win, vc_bin, QKVB,
                                  vc_Wout, vc_Wproj, ec_Wproj,
                                  WOUTB, WPVB, WPEB);

  // attention + out-proj (writes ATTNT transposed)
  attn_fwd<<<512,512,0,stream>>>(QKVB, OB);
  gemm_nt<2,128,1><<<dim3(128,2,1),256,0,stream>>>(OB, WOUTB, ATTNT, vc_bout,
                                                   8192,256,256);

  // scores = inc^T @ attn: 32e x 128d tiles, grid 768; VE=v*exp(v) bf16
  // + 48 exp-sum partials per column
  gemm_score<<<768,256,0,stream>>>(INCT, ATTNT, PART, SCORESB);

  // edge path: PART->1/L, p=VE/L staging, GEMM, LN; 16m tiles, grid 768
  gemm_ln_edge<<<768,256,0,stream>>>(SCORESB, WPVB, PART, vc_ln_g, vc_ln_b,
                                     vc_alpha, out_edge, BASET);

  // node path: 16m tiles, grid 512 — W0 = inc@base (K=1536) -> As2 LDS ->
  // @Wpe^T (K=256) + fused LN/blend
  gemm_node_fused<<<512,256,0,stream>>>(INCB, BASET, WPEB, ec_ln_g, ec_ln_b,
                                        ec_alpha, features, out_node);
}

// Round 14
// 242.459 us; speedup vs baseline: 1.0146x; 1.0146x over previous
//
#include <hip/hip_runtime.h>
#include <stdint.h>

// ============================================================================
// MessagePassing collapse:
//   e2 = (3+a_vc)*base,  base = LN((scores*softmax_e(scores)) @ Wp_vc^T)
//   n2 = (1+a)^3 * features + (1-a)((1+a)^2+(1+a)+1) * nb,  a = ec_alpha
//   nb = LN((inc @ base) @ Wp_ec^T)  (LN positive-scale-invariant)
//   EC's MHA is dead code.
// R23 (FINAL): R14 verbatim — the session's best-verified artifact (241.8us,
// baseline 260.5). R22's nontemporal out_inc store was refuted (prep 43.0 ->
// 44.6us) and is reverted. Structure: 5 launches —
//   1) qkv_prep: qkv GEMM (f32 reg-staged cvt_pk) + vectorized inc-prep
//      (64x64 tiles, float4/u64/uint4 stores, LDS f32[64][65] transpose)
//      + weight casts, one launch.
//   2) attn_fwd: 8-wave flash attn, max-free softmax, exp2, cvt_pk, setprio.
//   3) gemm_nt<2,128,1>: out-proj, transposed bf16 store.
//   4) gemm_score: inc^T@attn (32e x 128d, grid 768), VE=v*exp(v) + partials.
//   5) gemm_ln_edge / gemm_node_fused: fused GEMM+LN epilogues,
//      XCD-swizzled grids, XOR-swizzled LDS throughout.
// ============================================================================

#define DEV static __device__ __forceinline__

typedef __attribute__((ext_vector_type(8))) short bf16x8;
typedef __attribute__((ext_vector_type(4))) float f32x4;

DEV uint16_t f2bf(float x){
  union{float f; uint32_t u;} v; v.f=x;
  uint32_t r = v.u + 0x7fffu + ((v.u>>16)&1u);
  return (uint16_t)(r>>16);
}
DEV float bf2f(uint16_t b){
  union{uint32_t u; float f;} v; v.u=((uint32_t)b)<<16; return v.f;
}

DEV uint32_t cvtpk_bf16(float lo, float hi){
  uint32_t d;
  asm("v_cvt_pk_bf16_f32 %0, %1, %2" : "=v"(d) : "v"(lo), "v"(hi));
  return d;
}

#if __has_builtin(__builtin_amdgcn_exp2f)
DEV float exp2fast(float x){ return __builtin_amdgcn_exp2f(x); }
#else
DEV float exp2fast(float x){ return __expf(x * 0.6931471805599453f); }
#endif

#if __has_builtin(__builtin_amdgcn_global_load_lds)
#define HAVE_GLL 1
#else
#define HAVE_GLL 0
#endif

DEV void load_lds16(const uint16_t* g, void* l){
#if HAVE_GLL
  __builtin_amdgcn_global_load_lds((const __attribute__((address_space(1))) uint32_t*)g,
                                   (__attribute__((address_space(3))) uint32_t*)l, 16, 0, 0);
#else
  *(bf16x8*)l = *(const bf16x8*)g;
#endif
}

// ---------------------------------------------------------------------------
// Front launch, 3 block ranges:
//  [0,384):      qkv GEMM C[8192,768] = feats(f32)@Win(f32)^T + bin;
//                tile 128x128, BK=32, reg-staged f32->bf16 (cvt_pk).
//  [384,3456):   inc prep, vectorized: 64rows x 64cols per block
//                (float4 copy out + u64 bf16 + transposed uint4 bf16
//                via LDS f32[64][65]).
//  [3456,3648):  Wout/Wpv/Wpe f32->bf16 casts (49152 f4 units).
// ---------------------------------------------------------------------------
__global__ __launch_bounds__(256, 3)
void qkv_prep(const float* __restrict__ inc, float* __restrict__ out_inc,
              uint16_t* __restrict__ incb, uint16_t* __restrict__ incT,
              const float* __restrict__ feats, const float* __restrict__ win,
              const float* __restrict__ bias, uint16_t* __restrict__ qkvb,
              const float* __restrict__ wout, const float* __restrict__ wpv,
              const float* __restrict__ wpe,
              uint16_t* __restrict__ ob_w, uint16_t* __restrict__ ov_w,
              uint16_t* __restrict__ oe_w){
  __shared__ union {
    struct { short As[128*32]; short Bs[128*32]; } g;   // 16 KB
    float T[64*65];                                     // 16.6 KB
  } sm;
  const int tid = threadIdx.x;
  const int bx = blockIdx.x;

  if (bx < 384){
    // ---- qkv GEMM, BK=32 ----
    const int lane = tid & 63;
    const int w = tid >> 6;
    const int wm = w & 1, wn = w >> 1;
    const int r = lane & 15, q = lane >> 4;
    const int mtile = bx & 63, ntile = bx >> 6;   // 64 x 6
    const float* Fb = feats + (size_t)(mtile*128)*256;
    const float* Wb = win + (size_t)(ntile*128)*256;
    f32x4 acc[4][4];
#pragma unroll
    for (int i=0;i<4;++i)
#pragma unroll
      for (int j=0;j<4;++j) acc[i][j] = (f32x4){0.f,0.f,0.f,0.f};

    const int srow = tid >> 2;   // 0..63
    const int sblk = tid & 3;    // 0..3 (units of 8 bf16 within BK=32)

    for (int kb = 0; kb < 256; kb += 32){
#pragma unroll
      for (int i=0;i<2;++i){
        int row = srow + 64*i;
        const float* src = Fb + (size_t)row*256 + kb + sblk*8;
        float4 a0 = *(const float4*)src;
        float4 a1 = *(const float4*)(src+4);
        union{uint32_t u[4]; bf16x8 v8;} pk;
        pk.u[0]=cvtpk_bf16(a0.x,a0.y); pk.u[1]=cvtpk_bf16(a0.z,a0.w);
        pk.u[2]=cvtpk_bf16(a1.x,a1.y); pk.u[3]=cvtpk_bf16(a1.z,a1.w);
        *(bf16x8*)&sm.g.As[row*32 + (sblk ^ (row&3))*8] = pk.v8;
      }
#pragma unroll
      for (int i=0;i<2;++i){
        int row = srow + 64*i;
        const float* src = Wb + (size_t)row*256 + kb + sblk*8;
        float4 a0 = *(const float4*)src;
        float4 a1 = *(const float4*)(src+4);
        union{uint32_t u[4]; bf16x8 v8;} pk;
        pk.u[0]=cvtpk_bf16(a0.x,a0.y); pk.u[1]=cvtpk_bf16(a0.z,a0.w);
        pk.u[2]=cvtpk_bf16(a1.x,a1.y); pk.u[3]=cvtpk_bf16(a1.z,a1.w);
        *(bf16x8*)&sm.g.Bs[row*32 + (sblk ^ (row&3))*8] = pk.v8;
      }
      __syncthreads();
      bf16x8 af[4], bfr[4];
#pragma unroll
      for (int mt=0;mt<4;++mt){
        int m = wm*64 + mt*16 + r;
        af[mt] = *(const bf16x8*)&sm.g.As[m*32 + (q ^ (m&3))*8];
      }
#pragma unroll
      for (int nt=0;nt<4;++nt){
        int n = wn*64 + nt*16 + r;
        bfr[nt] = *(const bf16x8*)&sm.g.Bs[n*32 + (q ^ (n&3))*8];
      }
#pragma unroll
      for (int mt=0;mt<4;++mt)
#pragma unroll
        for (int nt=0;nt<4;++nt)
          acc[mt][nt] = __builtin_amdgcn_mfma_f32_16x16x32_bf16(af[mt], bfr[nt], acc[mt][nt], 0,0,0);
      __syncthreads();
    }

    const int gm0 = mtile*128 + wm*64;
    const int gn0 = ntile*128 + wn*64;
#pragma unroll
    for (int mt=0;mt<4;++mt){
#pragma unroll
      for (int nt=0;nt<4;++nt){
        int gn = gn0 + nt*16 + r;
        float bv = bias[gn];
#pragma unroll
        for (int reg=0;reg<4;++reg){
          int gm = gm0 + mt*16 + q*4 + reg;   // C/D: col=lane&15, row=quad*4+reg
          qkvb[(size_t)gm*768 + gn] = f2bf(acc[mt][nt][reg] + bv);
        }
      }
    }
  } else if (bx < 3456){
    // ---- inc prep, vectorized 64x64 tile ----
    int p = bx - 384;
    int x = p % 24;             // 64-col tile (1536/64)
    int t = p / 24;
    int y = t & 15;             // 64-row tile (1024/64)
    int b = t >> 4;             // batch
    int c0 = x*64, r0 = y*64;
    int tx = tid & 15, ty = tid >> 4;   // 16 x 16
    size_t base = (size_t)b*1024*1536;
#pragma unroll
    for (int jj=0;jj<4;++jj){
      int rl = ty + jj*16;
      size_t idx = base + (size_t)(r0+rl)*1536 + c0 + tx*4;
      float4 v = *(const float4*)&inc[idx];
      *(float4*)&out_inc[idx] = v;
      union{uint16_t u[4]; uint64_t q64;} pk;
      pk.u[0]=f2bf(v.x); pk.u[1]=f2bf(v.y); pk.u[2]=f2bf(v.z); pk.u[3]=f2bf(v.w);
      *(uint64_t*)&incb[idx] = pk.q64;
      float* Tp = &sm.T[rl*65 + tx*4];
      Tp[0]=v.x; Tp[1]=v.y; Tp[2]=v.z; Tp[3]=v.w;
    }
    __syncthreads();
    // transposed write: c = tid>>2 (0..63 e-rows), ms = (tid&3)*16 m-offset;
    // lanes 0-3 cover one row's 128B contiguously.
    int c = tid >> 2, ms = (tid & 3) * 16;
    size_t baseT = (size_t)b*1536*1024;
    uint16_t* dst = incT + baseT + (size_t)(c0+c)*1024 + r0 + ms;
    union{uint16_t u[8]; uint4 v4;} o0, o1;
#pragma unroll
    for (int j=0;j<8;++j) o0.u[j] = f2bf(sm.T[(ms+j)*65 + c]);
#pragma unroll
    for (int j=0;j<8;++j) o1.u[j] = f2bf(sm.T[(ms+8+j)*65 + c]);
    *(uint4*)dst = o0.v4;
    *(uint4*)(dst+8) = o1.v4;
  } else {
    // ---- weight casts: Wout/Wpv/Wpe, 16384 f4-units each ----
    int i = (bx - 3456)*256 + tid;
    const float* src; uint16_t* dst; int j;
    if (i < 16384){ src=wout; dst=ob_w; j=i; }
    else if (i < 32768){ src=wpv; dst=ov_w; j=i-16384; }
    else { src=wpe; dst=oe_w; j=i-32768; }
    float4 v = ((const float4*)src)[j];
    union { uint16_t u[4]; uint64_t q; } p;
    p.u[0]=f2bf(v.x); p.u[1]=f2bf(v.y); p.u[2]=f2bf(v.z); p.u[3]=f2bf(v.w);
    ((uint64_t*)dst)[j] = p.q;
  }
}

// ---------------------------------------------------------------------------
// NT bf16 GEMM (LDS-staged): C[M,N] = A[M,K]*B[N,K]^T (+bias).
// EPI 1 = transposed bf16 store (per-batch [N][1024]). Used for outproj.
// ---------------------------------------------------------------------------
template<int WM, int BK, int EPI>
__global__ __launch_bounds__(256, 3)
void gemm_nt(const uint16_t* __restrict__ A, const uint16_t* __restrict__ B,
             uint16_t* __restrict__ Cb, const float* __restrict__ bias,
             int M, int N, int K){
  constexpr int AROWS = WM*32;
  constexpr int UPR = BK/8;
  constexpr int RPP = 256/UPR;
  __shared__ short As[AROWS*BK];
  __shared__ short Bs[128*BK];
  const int tid = threadIdx.x;
  const int lane = tid & 63;
  const int w = tid >> 6;
  const int wm = w & 1, wn = w >> 1;
  const int r = lane & 15, q = lane >> 4;
  const uint16_t* Ab = A + (size_t)(blockIdx.x*AROWS)*K;
  const uint16_t* Bb = B + (size_t)(blockIdx.y*128)*K;
  f32x4 acc[WM][4];
#pragma unroll
  for (int i=0;i<WM;++i)
#pragma unroll
    for (int j=0;j<4;++j) acc[i][j] = (f32x4){0.f,0.f,0.f,0.f};

  const int srow = tid / UPR;
  const int sblk = tid % UPR;

  for (int kb = 0; kb < K; kb += BK){
#pragma unroll
    for (int i=0;i<AROWS/RPP;++i){
      int row = srow + RPP*i;
      int lblk = sblk ^ (row & (UPR-1));
      load_lds16(Ab + (size_t)row*K + kb + lblk*8, (char*)As + i*4096 + tid*16);
    }
#pragma unroll
    for (int i=0;i<128/RPP;++i){
      int row = srow + RPP*i;
      int lblk = sblk ^ (row & (UPR-1));
      load_lds16(Bb + (size_t)row*K + kb + lblk*8, (char*)Bs + i*4096 + tid*16);
    }
    __syncthreads();
#pragma unroll
    for (int kc=0;kc<BK/32;++kc){
      bf16x8 af[WM], bfr[4];
#pragma unroll
      for (int mt=0;mt<WM;++mt){
        int m = wm*(WM*16) + mt*16 + r;
        af[mt] = *(const bf16x8*)&As[m*BK + ((kc*4 + q) ^ (m&(UPR-1)))*8];
      }
#pragma unroll
      for (int nt=0;nt<4;++nt){
        int n = wn*64 + nt*16 + r;
        bfr[nt] = *(const bf16x8*)&Bs[n*BK + ((kc*4 + q) ^ (n&(UPR-1)))*8];
      }
#pragma unroll
      for (int mt=0;mt<WM;++mt)
#pragma unroll
        for (int nt=0;nt<4;++nt)
          acc[mt][nt] = __builtin_amdgcn_mfma_f32_16x16x32_bf16(af[mt], bfr[nt], acc[mt][nt], 0,0,0);
    }
    __syncthreads();
  }

  const int gm0 = blockIdx.x*AROWS + wm*(WM*16);
  const int gn0 = blockIdx.y*128 + wn*64;

  if constexpr (EPI == 1){
#pragma unroll
    for (int mt=0;mt<WM;++mt){
      int gmb = gm0 + mt*16 + q*4;
      size_t bb_ = (size_t)(gmb>>10)*(256*1024);
      int mm = gmb & 1023;
#pragma unroll
      for (int nt=0;nt<4;++nt){
        int gn = gn0 + nt*16 + r;
        float bv = bias ? bias[gn] : 0.f;
        union{uint16_t u[4]; uint64_t q64;} pk;
#pragma unroll
        for (int reg=0;reg<4;++reg) pk.u[reg] = f2bf(acc[mt][nt][reg] + bv);
        *(uint64_t*)(Cb + bb_ + (size_t)gn*1024 + mm) = pk.q64;
      }
    }
  } else {
#pragma unroll
    for (int mt=0;mt<WM;++mt){
#pragma unroll
      for (int nt=0;nt<4;++nt){
        int gn = gn0 + nt*16 + r;
        float bv = bias ? bias[gn] : 0.f;
#pragma unroll
        for (int reg=0;reg<4;++reg){
          int gm = gm0 + mt*16 + q*4 + reg;
          Cb[(size_t)gm*N + gn] = f2bf(acc[mt][nt][reg] + bv);
        }
      }
    }
  }
}

// ---------------------------------------------------------------------------
// scores GEMM: C[e,d] = incT[e,:].attnT[d,:] (K=1024). Tile 32e x 128d,
// 4 waves x 32 cols. Grid 768 = 8 batches * 48 etiles * 2 dhalves,
// XCD-swizzled. Writes VE=v*exp(v) bf16 + column exp-sum partials
// (48 partials per column, layout part[batch][48][256]).
// ---------------------------------------------------------------------------
__global__ __launch_bounds__(256, 4)
void gemm_score(const uint16_t* __restrict__ A,   // INCT flat [8*1536][1024]
                const uint16_t* __restrict__ B,   // ATTNT [8][256][1024]
                float* __restrict__ part,         // [8][48][256]
                uint16_t* __restrict__ VE){       // [8*1536][256]
  __shared__ short As[32*64];     // 4 KB
  __shared__ short Bs[128*64];    // 16 KB
  const int tid = threadIdx.x;
  const int lane = tid & 63;
  const int w = tid >> 6;
  const int r = lane & 15, q = lane >> 4;
  const int bx = (blockIdx.x & 7)*96 + (blockIdx.x >> 3);   // bijective, 768=8*96
  const int batch = bx / 96;
  const int t = bx % 96;
  const int etile = t >> 1, dh = t & 1;
  const uint16_t* Ab = A + (size_t)(batch*1536 + etile*32)*1024;
  const uint16_t* Bb = B + (size_t)(batch*256 + dh*128)*1024;

  f32x4 acc[2][2];
#pragma unroll
  for (int i=0;i<2;++i)
#pragma unroll
    for (int j=0;j<2;++j) acc[i][j] = (f32x4){0.f,0.f,0.f,0.f};

  const int srow = tid >> 3;   // 0..31
  const int sblk = tid & 7;

  for (int kb = 0; kb < 1024; kb += 64){
    { int lblk = sblk ^ (srow & 7);
      load_lds16(Ab + (size_t)srow*1024 + kb + lblk*8, (char*)As + tid*16); }
#pragma unroll
    for (int i=0;i<4;++i){
      int row = srow + 32*i;
      int lblk = sblk ^ (row & 7);
      load_lds16(Bb + (size_t)row*1024 + kb + lblk*8, (char*)Bs + i*4096 + tid*16);
    }
    __syncthreads();
#pragma unroll
    for (int kc=0;kc<2;++kc){
      bf16x8 af[2], bfr[2];
#pragma unroll
      for (int mt=0;mt<2;++mt){
        int m = mt*16 + r;
        af[mt] = *(const bf16x8*)&As[m*64 + ((kc*4 + q) ^ (m&7))*8];
      }
#pragma unroll
      for (int nt=0;nt<2;++nt){
        int n = w*32 + nt*16 + r;
        bfr[nt] = *(const bf16x8*)&Bs[n*64 + ((kc*4 + q) ^ (n&7))*8];
      }
#pragma unroll
      for (int mt=0;mt<2;++mt)
#pragma unroll
        for (int nt=0;nt<2;++nt)
          acc[mt][nt] = __builtin_amdgcn_mfma_f32_16x16x32_bf16(af[mt], bfr[nt], acc[mt][nt], 0,0,0);
    }
    __syncthreads();
  }

  const size_t er0 = (size_t)batch*1536 + etile*32;
#pragma unroll
  for (int nt=0;nt<2;++nt){
    int gn = dh*128 + w*32 + nt*16 + r;
    float s = 0.f;
#pragma unroll
    for (int mt=0;mt<2;++mt){
#pragma unroll
      for (int reg=0;reg<4;++reg){
        float v = acc[mt][nt][reg];
        float ev = __expf(v);
        s += ev;
        int row = mt*16 + q*4 + reg;
        VE[(er0 + row)*256 + gn] = f2bf(v*ev);
      }
    }
    s += __shfl_xor(s, 16);
    s += __shfl_xor(s, 32);
    if (q == 0) part[(size_t)(batch*48 + etile)*256 + gn] = s;
  }
}

// ---------------------------------------------------------------------------
// Edge path: A = VE * (1/L) staged (cvt_pk), L folded from 48 partials.
// Tile 16m x 256n (LN over full 256 in-block), grid 768 = 8*96, XCD-swizzled.
// Writes out_edge f32 + BASET bf16 [b][d][e].
// ---------------------------------------------------------------------------
__global__ __launch_bounds__(256, 4)
void gemm_ln_edge(const uint16_t* __restrict__ SB, const uint16_t* __restrict__ B,
                  const float* __restrict__ part, const float* __restrict__ g,
                  const float* __restrict__ bb, const float* __restrict__ alpha,
                  float* __restrict__ out, uint16_t* __restrict__ baset){
  __shared__ short As[16*64];     // 2 KB
  __shared__ short Bs[256*64];    // 32 KB
  __shared__ float lnS[4][16], lnQ[4][16];
  __shared__ float PLinv[256];
  const int tid = threadIdx.x;
  const int lane = tid & 63;
  const int w = tid >> 6;          // wave = d-strip 0..3
  const int r = lane & 15, q = lane >> 4;
  const int bx = (blockIdx.x & 7)*96 + (blockIdx.x >> 3);   // 768=8*96
  const int batch = bx / 96;

  {
    float s = 0.f;
#pragma unroll
    for (int i=0;i<48;++i) s += part[((size_t)batch*48 + i)*256 + tid];
    PLinv[tid] = 1.0f / s;
  }
  __syncthreads();

  f32x4 acc[4];
#pragma unroll
  for (int j=0;j<4;++j) acc[j] = (f32x4){0.f,0.f,0.f,0.f};

  const int srow = tid >> 3;   // 0..31 (A uses 0..15 via tid<128)
  const int sblk = tid & 7;

  for (int kb = 0; kb < 256; kb += 64){
    if (tid < 128){
      bf16x8 v = *(const bf16x8*)(SB + (size_t)(bx*16 + srow)*256 + kb + sblk*8);
      const float* Lp = &PLinv[kb + sblk*8];
      float xv[8];
#pragma unroll
      for (int j=0;j<8;++j) xv[j] = bf2f((uint16_t)v[j]) * Lp[j];
      union{uint32_t u[4]; bf16x8 v8;} pk;
      pk.u[0] = cvtpk_bf16(xv[0], xv[1]);
      pk.u[1] = cvtpk_bf16(xv[2], xv[3]);
      pk.u[2] = cvtpk_bf16(xv[4], xv[5]);
      pk.u[3] = cvtpk_bf16(xv[6], xv[7]);
      *(bf16x8*)&As[srow*64 + (sblk ^ (srow&7))*8] = pk.v8;
    }
#pragma unroll
    for (int i=0;i<8;++i){
      int row = srow + 32*i;
      int lblk = sblk ^ (row & 7);
      load_lds16(B + (size_t)row*256 + kb + lblk*8, (char*)Bs + i*4096 + tid*16);
    }
    __syncthreads();
#pragma unroll
    for (int kc=0;kc<2;++kc){
      bf16x8 af, bfr[4];
      { int m = r;
        af = *(const bf16x8*)&As[m*64 + ((kc*4 + q) ^ (m&7))*8]; }
#pragma unroll
      for (int nt=0;nt<4;++nt){
        int n = w*64 + nt*16 + r;
        bfr[nt] = *(const bf16x8*)&Bs[n*64 + ((kc*4 + q) ^ (n&7))*8];
      }
#pragma unroll
      for (int nt=0;nt<4;++nt)
        acc[nt] = __builtin_amdgcn_mfma_f32_16x16x32_bf16(af, bfr[nt], acc[nt], 0,0,0);
    }
    __syncthreads();
  }

  // cross-wave LN reduction (rows = q*4+reg, 16 rows)
  float rs[4], rq[4];
#pragma unroll
  for (int reg=0;reg<4;++reg){
    float s=0.f, s2=0.f;
#pragma unroll
    for (int nt=0;nt<4;++nt){
      float v = acc[nt][reg];
      s += v; s2 += v*v;
    }
#pragma unroll
    for (int off=1; off<16; off<<=1){ s += __shfl_xor(s,off); s2 += __shfl_xor(s2,off); }
    rs[reg]=s; rq[reg]=s2;
  }
  if (r == 0){
#pragma unroll
    for (int reg=0;reg<4;++reg){
      int row = q*4 + reg;
      lnS[w][row] = rs[reg];
      lnQ[w][row] = rq[reg];
    }
  }
  __syncthreads();

  const float c0 = 3.0f + alpha[0];
  float mu_[4], rstd_[4];
#pragma unroll
  for (int reg=0;reg<4;++reg){
    int row = q*4 + reg;
    float S = lnS[0][row]+lnS[1][row]+lnS[2][row]+lnS[3][row];
    float Q = lnQ[0][row]+lnQ[1][row]+lnQ[2][row]+lnQ[3][row];
    float mu = S * (1.f/256.f);
    float var = fmaxf(Q*(1.f/256.f) - mu*mu, 0.f);
    mu_[reg] = mu;
    rstd_[reg] = rsqrtf(var + 1e-5f);
  }

  int e0 = (bx % 96) * 16;
#pragma unroll
  for (int nt=0;nt<4;++nt){
    int gn = w*64 + nt*16 + r;
    float gv = g[gn], bv = bb[gn];
    union{uint16_t u[4]; uint64_t q64;} pk;
#pragma unroll
    for (int reg=0;reg<4;++reg){
      int row = q*4 + reg;
      size_t gm = (size_t)bx*16 + row;
      float o = ((acc[nt][reg]-mu_[reg])*rstd_[reg]*gv + bv) * c0;
      pk.u[reg] = f2bf(o);
      out[gm*256 + gn] = o;
    }
    int ee = e0 + q*4;
    *(uint64_t*)(baset + ((size_t)batch*256 + gn)*1536 + ee) = pk.q64;
  }
}

// ---------------------------------------------------------------------------
// Fused node path: 16m x 256d tiles, grid 512 = 8 batches * 64 m-tiles,
// XCD-swizzled.
//   phase 1: W0^T[d,m] = BASET[d,:].INCB[m,:] (K=1536) -> As2 bf16 swz
//   phase 2: C2^T[d',m] = WPEB[d',:].As2[m,:] (K=256)
//   epilogue: per-m LN over d' + blend with features.
// ---------------------------------------------------------------------------
__global__ __launch_bounds__(256, 3)
void gemm_node_fused(const uint16_t* __restrict__ inc,    // INCB [8][1024][1536]
                     const uint16_t* __restrict__ baset,  // [8][256][1536]
                     const uint16_t* __restrict__ wpe,    // [256][256]
                     const float* __restrict__ g, const float* __restrict__ bb,
                     const float* __restrict__ alpha,
                     const float* __restrict__ feats, float* __restrict__ out){
  __shared__ short Ws[256*64];    // 32KB
  __shared__ short As2[16*256];   // 8KB: W0 bf16, swizzled
  __shared__ short Is[16*64];     // 2KB: inc chunk; aliased lnS/lnQ later
  const int tid = threadIdx.x;
  const int lane = tid & 63;
  const int w = tid >> 6;
  const int r = lane & 15, q = lane >> 4;
  const int bx = (blockIdx.x & 7)*64 + (blockIdx.x >> 3);  // bijective, 512=8*64
  const int batch = bx >> 6;
  const int mt0 = (bx & 63) * 16;

  const int srow = tid >> 3;   // 0..31
  const int sblk = tid & 7;

  const uint16_t* Bb = baset + (size_t)batch*256*1536;
  const uint16_t* Ib = inc + ((size_t)batch*1024 + mt0)*1536;

  f32x4 acc1[4];
#pragma unroll
  for (int i=0;i<4;++i) acc1[i] = (f32x4){0.f,0.f,0.f,0.f};

  // ---- phase 1: K=1536 ----
  for (int kb = 0; kb < 1536; kb += 64){
#pragma unroll
    for (int i=0;i<8;++i){
      int row = srow + 32*i;
      int lblk = sblk ^ (row & 7);
      load_lds16(Bb + (size_t)row*1536 + kb + lblk*8, (char*)Ws + i*4096 + tid*16);
    }
    if (tid < 128){
      int lblk = sblk ^ (srow & 7);
      load_lds16(Ib + (size_t)srow*1536 + kb + lblk*8, (char*)Is + tid*16);
    }
    __syncthreads();
#pragma unroll
    for (int kc=0;kc<2;++kc){
      bf16x8 af[4], bfr;
#pragma unroll
      for (int mt=0;mt<4;++mt){
        int d = w*64 + mt*16 + r;
        af[mt] = *(const bf16x8*)&Ws[d*64 + ((kc*4 + q) ^ (d&7))*8];
      }
      { int m = r;
        bfr = *(const bf16x8*)&Is[m*64 + ((kc*4 + q) ^ (m&7))*8]; }
#pragma unroll
      for (int mt=0;mt<4;++mt)
        acc1[mt] = __builtin_amdgcn_mfma_f32_16x16x32_bf16(af[mt], bfr, acc1[mt], 0,0,0);
    }
    __syncthreads();
  }

  // ---- W0^T -> As2[m][d] bf16, 16B-unit XOR swizzle (j ^ (m&7)) ----
  // acc1[mt][reg] = W0^T[d][m], d = w*64+mt*16+q*4+reg, m = r.
#pragma unroll
  for (int mt=0;mt<4;++mt){
    int j = w*8 + mt*2 + (q>>1);
    int m = r;
    union{uint16_t u[4]; uint64_t q64;} pk;
#pragma unroll
    for (int reg=0;reg<4;++reg) pk.u[reg] = f2bf(acc1[mt][reg]);
    *(uint64_t*)((char*)As2 + m*512 + ((j ^ (m&7))<<4) + ((q&1)<<3)) = pk.q64;
  }

  // ---- phase 2: K=256, A = WPEB, B = As2 ----
  f32x4 acc2[4];
#pragma unroll
  for (int i=0;i<4;++i) acc2[i] = (f32x4){0.f,0.f,0.f,0.f};

  for (int kb = 0; kb < 256; kb += 64){
#pragma unroll
    for (int i=0;i<8;++i){
      int row = srow + 32*i;
      int lblk = sblk ^ (row & 7);
      load_lds16(wpe + (size_t)row*256 + kb + lblk*8, (char*)Ws + i*4096 + tid*16);
    }
    __syncthreads();   // orders As2 writes + Ws restage before reads
#pragma unroll
    for (int kc=0;kc<2;++kc){
      bf16x8 af[4], bfr;
#pragma unroll
      for (int mt=0;mt<4;++mt){
        int dp = w*64 + mt*16 + r;
        af[mt] = *(const bf16x8*)&Ws[dp*64 + ((kc*4 + q) ^ (dp&7))*8];
      }
      { int m = r;
        int jr = (kb>>3) + kc*4 + q;
        bfr = *(const bf16x8*)((char*)As2 + m*512 + ((jr ^ (m&7))<<4)); }
#pragma unroll
      for (int mt=0;mt<4;++mt)
        acc2[mt] = __builtin_amdgcn_mfma_f32_16x16x32_bf16(af[mt], bfr, acc2[mt], 0,0,0);
    }
    __syncthreads();
  }

  // ---- LN over d' (per column m = r), cross-wave via LDS (alias Is) ----
  float* lnS = (float*)Is;        // [4][16]
  float* lnQ = lnS + 64;          // [4][16]
  float s_, q_;
  {
    float s=0.f, s2=0.f;
#pragma unroll
    for (int mt=0;mt<4;++mt)
#pragma unroll
      for (int reg=0;reg<4;++reg){
        float v = acc2[mt][reg];
        s += v; s2 += v*v;
      }
    s += __shfl_xor(s,16); s2 += __shfl_xor(s2,16);
    s += __shfl_xor(s,32); s2 += __shfl_xor(s2,32);
    s_ = s; q_ = s2;
  }
  if (q == 0){
    lnS[w*16 + r] = s_;
    lnQ[w*16 + r] = q_;
  }
  __syncthreads();

  const float a = alpha[0];
  const float ap1 = 1.f + a;
  const float cn = (1.f - a)*(ap1*ap1 + ap1 + 1.f);
  const float cf = ap1*ap1*ap1;

  float mu_, rstd_;
  {
    int col = r;
    float S = lnS[col] + lnS[16+col] + lnS[32+col] + lnS[48+col];
    float Q = lnQ[col] + lnQ[16+col] + lnQ[32+col] + lnQ[48+col];
    float mu = S * (1.f/256.f);
    float var = fmaxf(Q*(1.f/256.f) - mu*mu, 0.f);
    mu_ = mu;
    rstd_ = rsqrtf(var + 1e-5f);
  }

  // ---- epilogue: out[m][d'] = cf*feats + cn*LN ----
#pragma unroll
  for (int mt=0;mt<4;++mt){
    int dp0 = w*64 + mt*16 + q*4;
    float4 gv = *(const float4*)&g[dp0];
    float4 bv = *(const float4*)&bb[dp0];
    int m = r;
    size_t gm = (size_t)batch*1024 + mt0 + m;
    float4 fv = *(const float4*)&feats[gm*256 + dp0];
    float4 ov;
    ov.x = cf*fv.x + cn*((acc2[mt][0]-mu_)*rstd_*gv.x + bv.x);
    ov.y = cf*fv.y + cn*((acc2[mt][1]-mu_)*rstd_*gv.y + bv.y);
    ov.z = cf*fv.z + cn*((acc2[mt][2]-mu_)*rstd_*gv.z + bv.z);
    ov.w = cf*fv.w + cn*((acc2[mt][3]-mu_)*rstd_*gv.w + bv.w);
    *(float4*)&out[gm*256 + dp0] = ov;
  }
}

// ---------------------------------------------------------------------------
// Attention: S^T = K*Q^T (A/B frags interchangeable), packed b64 P-store,
// scalar l. 512 thr = 8 waves x 16 q-rows. grid 512 (1D, XCD-swizzled).
// Max-free softmax; exp2 direct; cvt_pk P-pack; setprio around MFMA (T5).
// ---------------------------------------------------------------------------
DEV void stage_K(short* Kl, const uint16_t* __restrict__ qkv, size_t rowbase,
                 int c, int h, int kr){
  const uint16_t* kp = qkv + ((rowbase + c*256 + kr)*768 + 256 + h*32);
  int sz = (kr&3) ^ ((kr>>2)&1);
#pragma unroll
  for (int lb=0; lb<4; ++lb){
    bf16x8 v = *(const bf16x8*)(kp + lb*8);
    *(bf16x8*)&Kl[kr*32 + ((lb ^ sz))*8] = v;
  }
}

DEV void stage_V(short* VT, const uint16_t* __restrict__ qkv, size_t rowbase,
                 int c, int h, int t){
  int kvp = (t>>1)*2;
  int dhh = (t&1)*16;
  const uint16_t* v0 = qkv + ((rowbase + c*256 + kvp)*768 + 512 + h*32 + dhh);
  const uint16_t* v1 = v0 + 768;
  bf16x8 a0 = *(const bf16x8*)(v0);
  bf16x8 a1 = *(const bf16x8*)(v0+8);
  bf16x8 b0 = *(const bf16x8*)(v1);
  bf16x8 b1 = *(const bf16x8*)(v1+8);
  int blkbase = kvp>>3, off = kvp&7;
#pragma unroll
  for (int i=0;i<8;++i){
    int dh = dhh + i;
    uint32_t pack = (uint32_t)(uint16_t)a0[i] | ((uint32_t)(uint16_t)b0[i]<<16);
    *(uint32_t*)&VT[dh*256 + ((blkbase ^ (dh&7))*8) + off] = pack;
  }
#pragma unroll
  for (int i=0;i<8;++i){
    int dh = dhh + 8 + i;
    uint32_t pack = (uint32_t)(uint16_t)a1[i] | ((uint32_t)(uint16_t)b1[i]<<16);
    *(uint32_t*)&VT[dh*256 + ((blkbase ^ (dh&7))*8) + off] = pack;
  }
}

__global__ __launch_bounds__(512)
void attn_fwd(const uint16_t* __restrict__ qkv, uint16_t* __restrict__ O){
  __shared__ short Kl[256*32];
  __shared__ short VT[32*256];
  __shared__ short Pl[8][16*36];
  const int tid = threadIdx.x, lane = tid&63, w = tid>>6;
  const int r = lane&15, q = lane>>4;
  const int logical = (blockIdx.x & 7)*64 + (blockIdx.x >> 3); // 512=8*64 bijective
  const int bh = logical >> 3, qc = logical & 7;
  const int b = bh>>3, h = bh&7;
  const int q0 = qc*128 + w*16;
  const size_t rowbase = (size_t)b*1024;

  bf16x8 aq;
  {
    // 1/sqrt(32) * log2(e): p = exp2(S_mfma)
    const float qscale = 0.25505654380651023f;
    const uint16_t* p = qkv + ((rowbase + q0 + r)*768 + h*32 + q*8);
    bf16x8 t = *(const bf16x8*)p;
#pragma unroll
    for (int j=0;j<8;++j)
      t[j] = (short)f2bf(bf2f((uint16_t)t[j]) * qscale);
    aq = t;
  }

  f32x4 o[2];
  o[0]=(f32x4){0.f,0.f,0.f,0.f}; o[1]=(f32x4){0.f,0.f,0.f,0.f};
  float l = 0.f;

  for (int c=0;c<4;++c){
    __syncthreads();
    if (tid < 256) stage_K(Kl, qkv, rowbase, c, h, tid);
    else           stage_V(VT, qkv, rowbase, c, h, tid-256);
    __syncthreads();
    for (int s32=0; s32<8; ++s32){
#pragma unroll
      for (int t2=0;t2<2;++t2){
        int rn = s32*32 + t2*16 + r;
        int sz = (rn&3) ^ ((rn>>2)&1);
        bf16x8 bk = *(const bf16x8*)&Kl[rn*32 + ((q ^ sz))*8];
        f32x4 z = (f32x4){0.f,0.f,0.f,0.f};
        __builtin_amdgcn_s_setprio(1);
        f32x4 st = __builtin_amdgcn_mfma_f32_16x16x32_bf16(bk, aq, z, 0,0,0);
        __builtin_amdgcn_s_setprio(0);
        float p0 = exp2fast(st[0]);
        float p1 = exp2fast(st[1]);
        float p2 = exp2fast(st[2]);
        float p3 = exp2fast(st[3]);
        l += (p0+p1)+(p2+p3);
        union{uint32_t u[2]; uint64_t q64;} pk;
        pk.u[0] = cvtpk_bf16(p0, p1);
        pk.u[1] = cvtpk_bf16(p2, p3);
        *(uint64_t*)&Pl[w][r*36 + t2*16 + q*4] = pk.q64;
      }
      bf16x8 bv[2];
#pragma unroll
      for (int db=0;db<2;++db){
        int dh = db*16 + r;
        bv[db] = *(const bf16x8*)&VT[dh*256 + (((s32*4 + q) ^ (dh&7)))*8];
      }
      bf16x8 ap = *(const bf16x8*)&Pl[w][r*36 + q*8];
      __builtin_amdgcn_s_setprio(1);
#pragma unroll
      for (int db=0;db<2;++db)
        o[db] = __builtin_amdgcn_mfma_f32_16x16x32_bf16(ap, bv[db], o[db], 0,0,0);
      __builtin_amdgcn_s_setprio(0);
    }
  }

  l += __shfl_xor(l, 16);
  l += __shfl_xor(l, 32);
#pragma unroll
  for (int db=0;db<2;++db)
#pragma unroll
    for (int reg=0;reg<4;++reg){
      float li = __shfl(l, q*4 + reg);
      int qr = q0 + q*4 + reg;
      O[(rowbase + qr)*256 + h*32 + db*16 + r] = f2bf(o[db][reg] / li);
    }
}

// ===========================================================================
extern "C" void kernel_launch(void* const* d_in, const int* in_sizes, int n_in,
                              void* d_out, int out_size, void* d_ws, size_t ws_size,
                              hipStream_t stream){
  const float* features = (const float*)d_in[0];
  const float* inc      = (const float*)d_in[1];
  const float* vc_Win   = (const float*)d_in[2];
  const float* vc_bin   = (const float*)d_in[3];
  const float* vc_Wout  = (const float*)d_in[4];
  const float* vc_bout  = (const float*)d_in[5];
  const float* vc_Wproj = (const float*)d_in[6];
  const float* vc_ln_g  = (const float*)d_in[7];
  const float* vc_ln_b  = (const float*)d_in[8];
  const float* vc_alpha = (const float*)d_in[9];
  const float* ec_Wproj = (const float*)d_in[14];
  const float* ec_ln_g  = (const float*)d_in[15];
  const float* ec_ln_b  = (const float*)d_in[16];
  const float* ec_alpha = (const float*)d_in[17];

  float* out = (float*)d_out;
  float* out_node = out;                 // [8,1024,256]
  float* out_edge = out + 2097152;       // [8,1536,256]
  float* out_inc  = out + 5242880;       // [8,1024,1536]

  char* ws = (char*)d_ws;
  float*    PART   = (float*)   (ws + 0);          // 393,216 (8*48*256*4)
  uint16_t* WOUTB  = (uint16_t*)(ws + 4587520);    // 131,072
  uint16_t* WPVB   = (uint16_t*)(ws + 4718592);    // 131,072
  uint16_t* WPEB   = (uint16_t*)(ws + 4849664);    // 131,072
  uint16_t* INCB   = (uint16_t*)(ws + 4988928);    // 25,165,824
  uint16_t* INCT   = (uint16_t*)(ws + 30154752);   // 25,165,824
  uint16_t* QKVB   = (uint16_t*)(ws + 55320576);   // 12,582,912
  uint16_t* SCORESB= (uint16_t*)(ws + 55320576);   // alias: QKVB dead after attn
  uint16_t* OB     = (uint16_t*)(ws + 67903488);   // 4,194,304
  uint16_t* ATTNT  = (uint16_t*)(ws + 72097792);   // 4,194,304
  uint16_t* BASET  = (uint16_t*)(ws + 82583552);   // 6,291,456 (~89 MB total)

  // front launch: qkv GEMM (f32 sources) + vectorized inc-prep + weight casts
  qkv_prep<<<3648,256,0,stream>>>(inc, out_inc, INCB, INCT,
                                  features, vc_Win, vc_bin, QKVB,
                                  vc_Wout, vc_Wproj, ec_Wproj,
                                  WOUTB, WPVB, WPEB);

  // attention + out-proj (writes ATTNT transposed)
  attn_fwd<<<512,512,0,stream>>>(QKVB, OB);
  gemm_nt<2,128,1><<<dim3(128,2,1),256,0,stream>>>(OB, WOUTB, ATTNT, vc_bout,
                                                   8192,256,256);

  // scores = inc^T @ attn: 32e x 128d tiles, grid 768; VE=v*exp(v) bf16
  // + 48 exp-sum partials per column
  gemm_score<<<768,256,0,stream>>>(INCT, ATTNT, PART, SCORESB);

  // edge path: PART->1/L, p=VE/L staging, GEMM, LN; 16m tiles, grid 768
  gemm_ln_edge<<<768,256,0,stream>>>(SCORESB, WPVB, PART, vc_ln_g, vc_ln_b,
                                     vc_alpha, out_edge, BASET);

  // node path: 16m tiles, grid 512 — W0 = inc@base (K=1536) -> As2 LDS ->
  // @Wpe^T (K=256) + fused LN/blend
  gemm_node_fused<<<512,256,0,stream>>>(INCB, BASET, WPEB, ec_ln_g, ec_ln_b,
                                        ec_alpha, features, out_node);
}